// Round 2
// baseline (808.005 us; speedup 1.0000x reference)
//
#include <hip/hip_runtime.h>

#define C 19
#define DCH 128
#define HWSZ 65536
#define TPB 256

// ws float offsets
#define WS_SUMS  0      // 2432 floats: sums[d*19+c]
#define WS_CNT   2432   // 19
#define WS_VAR   2451   // 19
#define WS_MEANS 2560   // 2432: meansT[d*19+c]
#define WS_VALID 4992   // 19
#define WS_SCAL  5011   // 3: loss_reg, loss_dist, t
#define WS_ZERO_END 2470

__global__ void k0_init(float* __restrict__ ws) {
    int i = blockIdx.x * blockDim.x + threadIdx.x;
    if (i < WS_ZERO_END) ws[i] = 0.f;
}

// Pass 1 (rewritten): per-class sums + counts with ZERO per-element atomics.
// 1024 blocks x 256 threads. Each block owns 512 pixels x all 128 channels.
// Thread t owns channel d = t>>1, pixel-half h = t&1; accumulates sums[d][c]
// in 19 registers via compare-select. Feats staged through LDS (transposed,
// pad 68) so global loads stay coalesced while compute reads channel-major.
#define K1_NB   1024
#define K1_PPB  512            // pixels per block
#define K1_Q    64             // pixels per stage
#define K1_NS   (K1_PPB / K1_Q)  // 8 stages
#define TPAD    68             // LDS row stride (floats), %32==4 -> mild aliasing

__global__ __launch_bounds__(TPB) void k1_sums(const float* __restrict__ feats,
                                               const int* __restrict__ labels,
                                               float* __restrict__ ws) {
    __shared__ float tile[DCH * TPAD];   // 34816 B
    __shared__ int   llab[K1_PPB];       // 2048 B
    __shared__ float lcnt[C];

    const int t = threadIdx.x;
    const int blk = blockIdx.x;
    const int b = blk >> 7;                    // 128 blocks per image
    const int p_base = (blk & 127) * K1_PPB;

    if (t < C) lcnt[t] = 0.f;
    __syncthreads();

    // stage labels + per-class counts (once per block)
    if (t < K1_PPB / 4) {
        int4 l4 = *reinterpret_cast<const int4*>(labels + b * HWSZ + p_base + t * 4);
        *reinterpret_cast<int4*>(&llab[t * 4]) = l4;
        if (l4.x >= 0) atomicAdd(&lcnt[l4.x], 1.f);
        if (l4.y >= 0) atomicAdd(&lcnt[l4.y], 1.f);
        if (l4.z >= 0) atomicAdd(&lcnt[l4.z], 1.f);
        if (l4.w >= 0) atomicAdd(&lcnt[l4.w], 1.f);
    }

    float acc[C];
#pragma unroll
    for (int c = 0; c < C; ++c) acc[c] = 0.f;

    const int d_own = t >> 1;
    const int h = t & 1;
    const int ld_r0 = t >> 4;           // staging: rows r0, r0+16, ... (8 iters)
    const int ld_c4 = (t & 15) * 4;     // staging: 4-float column group

    for (int s = 0; s < K1_NS; ++s) {
        __syncthreads();   // previous compute done (and llab visible at s=0)
        // stage 128 x 64 floats, coalesced (4 rows x 256B per wave)
        const float* fs = feats + (size_t)b * DCH * HWSZ + p_base + s * K1_Q + ld_c4;
#pragma unroll
        for (int rr = 0; rr < DCH; rr += 16) {
            float4 x = *reinterpret_cast<const float4*>(fs + (size_t)(rr + ld_r0) * HWSZ);
            *reinterpret_cast<float4*>(&tile[(rr + ld_r0) * TPAD + ld_c4]) = x;
        }
        __syncthreads();
        // compute: thread owns channel d_own, walks 32 pixels (its half)
        const float* trow = &tile[d_own * TPAD + h * 32];
        const int* lrow = &llab[s * K1_Q + h * 32];
#pragma unroll
        for (int j = 0; j < 32; j += 4) {
            float4 x = *reinterpret_cast<const float4*>(trow + j);
            int4 l = *reinterpret_cast<const int4*>(lrow + j);
#pragma unroll
            for (int c = 0; c < C; ++c) {
                acc[c] += (l.x == c ? x.x : 0.f);
                acc[c] += (l.y == c ? x.y : 0.f);
                acc[c] += (l.z == c ? x.z : 0.f);
                acc[c] += (l.w == c ? x.w : 0.f);
            }
        }
    }

    // flush: pair-reduce (h==1 -> LDS, h==0 adds) then global atomics
    __syncthreads();
    float* scr = tile;   // reuse: 128*19 floats
    if (h == 1) {
#pragma unroll
        for (int c = 0; c < C; ++c) scr[d_own * C + c] = acc[c];
    }
    __syncthreads();
    if (h == 0) {
#pragma unroll
        for (int c = 0; c < C; ++c)
            atomicAdd(&ws[WS_SUMS + d_own * C + c], acc[c] + scr[d_own * C + c]);
    }
    if (t < C) atomicAdd(&ws[WS_CNT + t], lcnt[t]);
}

// Pass 2: means, valid mask, loss_reg, loss_dist, t. Single block. (unchanged)
__global__ __launch_bounds__(TPB) void k2_means(float* __restrict__ ws) {
    __shared__ float lm[DCH * C];
    __shared__ float lcnt[C];
    __shared__ float lvalid[C];
    __shared__ float lreg;
    __shared__ float ldist;
    __shared__ int   llast;
    __shared__ float ltv;
    int t = threadIdx.x;
    if (t == 0) { lreg = 0.f; ldist = 0.f; }
    if (t < C) {
        float c = ws[WS_CNT + t];
        lcnt[t] = c;
        lvalid[t] = (c > 100.f) ? 1.f : 0.f;
    }
    __syncthreads();
    for (int i = t; i < DCH * C; i += TPB) {
        int c = i % C;
        float m = ws[WS_SUMS + i] / fmaxf(lcnt[c], 1.f);
        lm[i] = m;
        ws[WS_MEANS + i] = m;
    }
    if (t == 0) {
        float tv = 0.f; int last = -1;
        for (int c2 = 0; c2 < C; ++c2) if (lvalid[c2] > 0.5f) { tv += 1.f; last = c2; }
        ltv = tv; llast = last;
    }
    __syncthreads();
    if (t < C) {
        float s = 0.f;
        for (int d = 0; d < DCH; ++d) { float m = lm[d * C + t]; s += m * m; }
        float nrm = (s > 0.f) ? sqrtf(s) : 0.f;
        if (lvalid[t] > 0.5f) atomicAdd(&lreg, nrm);
    }
    for (int pr = t; pr < C * C; pr += TPB) {
        int a = pr / C, b2 = pr % C;
        if (lvalid[a] > 0.5f && lvalid[b2] > 0.5f && b2 != llast) {
            float s = 0.f;
            for (int d = 0; d < DCH; ++d) {
                float df = lm[d * C + a] - lm[d * C + b2];
                s += df * df;
            }
            float nrm = (s > 0.f) ? sqrtf(s) : 0.f;
            float hd = fmaxf(3.0f - nrm, 0.f);   // 2*DELTA_D = 3.0
            atomicAdd(&ldist, hd * hd);
        }
    }
    __syncthreads();
    if (t < C) ws[WS_VALID + t] = lvalid[t];
    if (t == 0) {
        ws[WS_SCAL + 0] = lreg;
        ws[WS_SCAL + 1] = ldist;
        ws[WS_SCAL + 2] = ltv;
    }
}

// Pass 3: per-pixel hinged distance to class mean, per-class accumulate. (unchanged)
__global__ __launch_bounds__(TPB) void k3_var(const float* __restrict__ feats,
                                              const int* __restrict__ labels,
                                              float* __restrict__ ws) {
    __shared__ float lm[DCH * C];
    __shared__ float lvalid[C];
    __shared__ float lvar[C];
    int t = threadIdx.x;
    for (int i = t; i < DCH * C; i += TPB) lm[i] = ws[WS_MEANS + i];
    if (t < C) { lvalid[t] = ws[WS_VALID + t]; lvar[t] = 0.f; }
    __syncthreads();

    int g = blockIdx.x;
    int b = g >> 6;
    int p = ((g & 63) << 10) + (t << 2);
    const int4 lab4 = *reinterpret_cast<const int4*>(labels + b * HWSZ + p);
    int l0 = lab4.x < 0 ? 0 : lab4.x;
    int l1 = lab4.y < 0 ? 0 : lab4.y;
    int l2 = lab4.z < 0 ? 0 : lab4.z;
    int l3 = lab4.w < 0 ? 0 : lab4.w;
    const float* fb = feats + (size_t)b * DCH * HWSZ + p;
    float a0 = 0.f, a1 = 0.f, a2 = 0.f, a3 = 0.f;
#pragma unroll 8
    for (int d = 0; d < DCH; ++d) {
        float4 x = *reinterpret_cast<const float4*>(fb + (size_t)d * HWSZ);
        int off = d * C;
        float d0 = x.x - lm[off + l0]; a0 = fmaf(d0, d0, a0);
        float d1 = x.y - lm[off + l1]; a1 = fmaf(d1, d1, a1);
        float d2 = x.z - lm[off + l2]; a2 = fmaf(d2, d2, a2);
        float d3 = x.w - lm[off + l3]; a3 = fmaf(d3, d3, a3);
    }
    auto hinge2 = [&](float a, int rawlab, int l) -> float {
        float nrm = (a > 0.f) ? sqrtf(a) : 0.f;
        float h = fmaxf(nrm - 0.5f, 0.f);      // DELTA_V = 0.5
        float v = h * h;
        return (rawlab >= 0 && lvalid[l] > 0.5f) ? v : 0.f;
    };
    atomicAdd(&lvar[l0], hinge2(a0, lab4.x, l0));
    atomicAdd(&lvar[l1], hinge2(a1, lab4.y, l1));
    atomicAdd(&lvar[l2], hinge2(a2, lab4.z, l2));
    atomicAdd(&lvar[l3], hinge2(a3, lab4.w, l3));
    __syncthreads();
    if (t < C) atomicAdd(&ws[WS_VAR + t], lvar[t]);
}

// Pass 4: final scalar. (unchanged)
__global__ void k4_final(const float* __restrict__ ws, float* __restrict__ out) {
    if (threadIdx.x == 0) {
        float loss_var = 0.f;
        for (int c = 0; c < C; ++c) {
            float cnt = ws[WS_CNT + c];
            float v = ws[WS_VAR + c] / fmaxf(cnt, 1.f);
            if (ws[WS_VALID + c] > 0.5f) loss_var += v;
        }
        float reg  = ws[WS_SCAL + 0];
        float dist = ws[WS_SCAL + 1];
        float tv   = ws[WS_SCAL + 2];
        float loss = loss_var / tv + dist / (tv * (tv - 1.0f)) + 0.001f * reg / tv;
        out[0] = loss;
    }
}

extern "C" void kernel_launch(void* const* d_in, const int* in_sizes, int n_in,
                              void* d_out, int out_size, void* d_ws, size_t ws_size,
                              hipStream_t stream) {
    const float* feats  = (const float*)d_in[0];
    const int*   labels = (const int*)d_in[1];
    float* ws  = (float*)d_ws;
    float* out = (float*)d_out;

    hipLaunchKernelGGL(k0_init,  dim3((WS_ZERO_END + 255) / 256), dim3(256), 0, stream, ws);
    hipLaunchKernelGGL(k1_sums,  dim3(K1_NB), dim3(TPB), 0, stream, feats, labels, ws);
    hipLaunchKernelGGL(k2_means, dim3(1),   dim3(TPB), 0, stream, ws);
    hipLaunchKernelGGL(k3_var,   dim3(512), dim3(TPB), 0, stream, feats, labels, ws);
    hipLaunchKernelGGL(k4_final, dim3(1),   dim3(64),  0, stream, ws, out);
}

// Round 3
// 455.926 us; speedup vs baseline: 1.7722x; 1.7722x over previous
//
#include <hip/hip_runtime.h>

#define C 19
#define DCH 128
#define HWSZ 65536
#define TPB 256

// ws float offsets
#define WS_SUMS  0      // 2432 floats: sums[d*19+c]
#define WS_CNT   2432   // 19
#define WS_VAR   2451   // 19
#define WS_MEANS 2560   // 2432: means[d*19+c]
#define WS_VALID 4992   // 19
#define WS_SCAL  5011   // 3: loss_reg, loss_dist, t
#define WS_ZERO_END 2470

__global__ void k0_init(float* __restrict__ ws) {
    int i = blockIdx.x * blockDim.x + threadIdx.x;
    if (i < WS_ZERO_END) ws[i] = 0.f;
}

// ---------------------------------------------------------------------------
// Pass 1: per-class sums + counts.
// 2048 blocks x 256 thr. Block = (image b, pixel-range r of 4096, d-group of 8).
// Wave w handles d = dg*8 + w and dg*8 + 4 + w over the whole range: global
// loads are lane-consecutive float4 (1KB/instr, coalesced), batched 4-deep for
// MLP. Labels staged once per block in LDS. acc[19] in registers via
// compare-select; flush = wave shuffle-reduce + 19-lane global atomic.
// ---------------------------------------------------------------------------
#define K1_NB  2048
#define K1_RPX 4096

__global__ __launch_bounds__(TPB) void k1_sums(const float* __restrict__ feats,
                                               const int* __restrict__ labels,
                                               float* __restrict__ ws) {
    __shared__ int llab[K1_RPX];   // 16 KB

    const int t = threadIdx.x;
    const int lane = t & 63;
    const int w = t >> 6;
    const int bid = blockIdx.x;
    const int b  = bid >> 8;          // 256 blocks per image
    const int r  = (bid >> 4) & 15;   // 16 ranges of 4096 px
    const int dg = bid & 15;          // 16 d-groups of 8

    // stage labels (coalesced int4), keep own 16 in regs for counting
    const int* lb = labels + b * HWSZ + r * K1_RPX;
    int4 myl[4];
#pragma unroll
    for (int u = 0; u < 4; ++u) {
        int4 v = *reinterpret_cast<const int4*>(lb + (u * TPB + t) * 4);
        myl[u] = v;
        *reinterpret_cast<int4*>(&llab[(u * TPB + t) * 4]) = v;
    }
    __syncthreads();

    // counts: only dg==0 blocks contribute (labels are re-staged 16x)
    if (dg == 0) {
        float cr[C];
#pragma unroll
        for (int c = 0; c < C; ++c) cr[c] = 0.f;
#pragma unroll
        for (int u = 0; u < 4; ++u) {
#pragma unroll
            for (int c = 0; c < C; ++c) {
                cr[c] += (myl[u].x == c ? 1.f : 0.f);
                cr[c] += (myl[u].y == c ? 1.f : 0.f);
                cr[c] += (myl[u].z == c ? 1.f : 0.f);
                cr[c] += (myl[u].w == c ? 1.f : 0.f);
            }
        }
#pragma unroll
        for (int c = 0; c < C; ++c)
            for (int m = 1; m < 64; m <<= 1) cr[c] += __shfl_xor(cr[c], m);
        float v = cr[0];
#pragma unroll
        for (int c = 1; c < C; ++c) v = (lane == c) ? cr[c] : v;
        if (lane < C) atomicAdd(&ws[WS_CNT + lane], v);
    }

    // two d's per wave
#pragma unroll
    for (int dd = 0; dd < 2; ++dd) {
        const int d = dg * 8 + dd * 4 + w;
        const float* fp = feats + (((size_t)(b * DCH + d)) << 16) + r * K1_RPX;
        float acc[C];
#pragma unroll
        for (int c = 0; c < C; ++c) acc[c] = 0.f;

        for (int jb = 0; jb < 16; jb += 4) {
            float4 x[4]; int4 l[4];
#pragma unroll
            for (int u = 0; u < 4; ++u) {
                x[u] = *reinterpret_cast<const float4*>(fp + (jb + u) * 256 + lane * 4);
                l[u] = *reinterpret_cast<const int4*>(&llab[((jb + u) * 64 + lane) * 4]);
            }
#pragma unroll
            for (int u = 0; u < 4; ++u) {
#pragma unroll
                for (int c = 0; c < C; ++c) {
                    acc[c] += (l[u].x == c ? x[u].x : 0.f);
                    acc[c] += (l[u].y == c ? x[u].y : 0.f);
                    acc[c] += (l[u].z == c ? x[u].z : 0.f);
                    acc[c] += (l[u].w == c ? x[u].w : 0.f);
                }
            }
        }
        // wave-reduce 19 values, then one 19-lane atomic instruction
#pragma unroll
        for (int c = 0; c < C; ++c)
            for (int m = 1; m < 64; m <<= 1) acc[c] += __shfl_xor(acc[c], m);
        float v = acc[0];
#pragma unroll
        for (int c = 1; c < C; ++c) v = (lane == c) ? acc[c] : v;
        if (lane < C) atomicAdd(&ws[WS_SUMS + d * C + lane], v);
    }
}

// Pass 2: means, valid mask, loss_reg, loss_dist, t. Single block. (unchanged)
__global__ __launch_bounds__(TPB) void k2_means(float* __restrict__ ws) {
    __shared__ float lm[DCH * C];
    __shared__ float lcnt[C];
    __shared__ float lvalid[C];
    __shared__ float lreg;
    __shared__ float ldist;
    __shared__ int   llast;
    __shared__ float ltv;
    int t = threadIdx.x;
    if (t == 0) { lreg = 0.f; ldist = 0.f; }
    if (t < C) {
        float c = ws[WS_CNT + t];
        lcnt[t] = c;
        lvalid[t] = (c > 100.f) ? 1.f : 0.f;
    }
    __syncthreads();
    for (int i = t; i < DCH * C; i += TPB) {
        int c = i % C;
        float m = ws[WS_SUMS + i] / fmaxf(lcnt[c], 1.f);
        lm[i] = m;
        ws[WS_MEANS + i] = m;
    }
    if (t == 0) {
        float tv = 0.f; int last = -1;
        for (int c2 = 0; c2 < C; ++c2) if (lvalid[c2] > 0.5f) { tv += 1.f; last = c2; }
        ltv = tv; llast = last;
    }
    __syncthreads();
    if (t < C) {
        float s = 0.f;
        for (int d = 0; d < DCH; ++d) { float m = lm[d * C + t]; s += m * m; }
        float nrm = (s > 0.f) ? sqrtf(s) : 0.f;
        if (lvalid[t] > 0.5f) atomicAdd(&lreg, nrm);
    }
    for (int pr = t; pr < C * C; pr += TPB) {
        int a = pr / C, b2 = pr % C;
        if (lvalid[a] > 0.5f && lvalid[b2] > 0.5f && b2 != llast) {
            float s = 0.f;
            for (int d = 0; d < DCH; ++d) {
                float df = lm[d * C + a] - lm[d * C + b2];
                s += df * df;
            }
            float nrm = (s > 0.f) ? sqrtf(s) : 0.f;
            float hd = fmaxf(3.0f - nrm, 0.f);   // 2*DELTA_D = 3.0
            atomicAdd(&ldist, hd * hd);
        }
    }
    __syncthreads();
    if (t < C) ws[WS_VALID + t] = lvalid[t];
    if (t == 0) {
        ws[WS_SCAL + 0] = lreg;
        ws[WS_SCAL + 1] = ldist;
        ws[WS_SCAL + 2] = ltv;
    }
}

// ---------------------------------------------------------------------------
// Pass 3: per-pixel hinged distance to class mean.
// 2048 blocks x 256 thr (8 blocks/CU, 32 waves/CU). Thread = (quad, d-quarter):
// 32 independent float4 loads, batched 8-deep. Partial sums combined across
// the 4 d-quarters with shfl_xor. Means in LDS padded to stride 20.
// ---------------------------------------------------------------------------
#define K3_NB 2048
#define MPAD 20

__global__ __launch_bounds__(TPB) void k3_var(const float* __restrict__ feats,
                                              const int* __restrict__ labels,
                                              float* __restrict__ ws) {
    __shared__ float lmS[DCH * MPAD];   // 10240 B, padded
    __shared__ float lvalid[C];
    __shared__ float lvar[C];
    const int t = threadIdx.x;
    for (int i = t; i < DCH * C; i += TPB) {
        int d = i / C, c = i - d * C;
        lmS[d * MPAD + c] = ws[WS_MEANS + i];
    }
    if (t < C) { lvalid[t] = ws[WS_VALID + t]; lvar[t] = 0.f; }
    __syncthreads();

    const int qloc = t >> 2;                 // 0..63
    const int k = t & 3;                     // d-quarter
    const int q = blockIdx.x * 64 + qloc;    // global quad
    const int b = q >> 14;                   // 16384 quads per image
    const int p = (q & 16383) * 4;

    const int4 lab4 = *reinterpret_cast<const int4*>(labels + b * HWSZ + p);
    const int l0 = lab4.x < 0 ? 0 : lab4.x;
    const int l1 = lab4.y < 0 ? 0 : lab4.y;
    const int l2 = lab4.z < 0 ? 0 : lab4.z;
    const int l3 = lab4.w < 0 ? 0 : lab4.w;

    const float* fb = feats + (((size_t)(b * DCH + k * 32)) << 16) + p;
    float a0 = 0.f, a1 = 0.f, a2 = 0.f, a3 = 0.f;
    for (int i = 0; i < 32; i += 8) {
        float4 xb[8];
#pragma unroll
        for (int u = 0; u < 8; ++u)
            xb[u] = *reinterpret_cast<const float4*>(fb + ((size_t)(i + u) << 16));
#pragma unroll
        for (int u = 0; u < 8; ++u) {
            const float* mr = &lmS[(k * 32 + i + u) * MPAD];
            float d0 = xb[u].x - mr[l0]; a0 = fmaf(d0, d0, a0);
            float d1 = xb[u].y - mr[l1]; a1 = fmaf(d1, d1, a1);
            float d2 = xb[u].z - mr[l2]; a2 = fmaf(d2, d2, a2);
            float d3 = xb[u].w - mr[l3]; a3 = fmaf(d3, d3, a3);
        }
    }
    // combine the 4 d-quarters (lanes t, t^1, t^2, t^3 share a quad)
    a0 += __shfl_xor(a0, 1); a0 += __shfl_xor(a0, 2);
    a1 += __shfl_xor(a1, 1); a1 += __shfl_xor(a1, 2);
    a2 += __shfl_xor(a2, 1); a2 += __shfl_xor(a2, 2);
    a3 += __shfl_xor(a3, 1); a3 += __shfl_xor(a3, 2);

    if (k == 0) {
        auto hinge2 = [&](float a, int rawlab, int l) -> float {
            float nrm = (a > 0.f) ? sqrtf(a) : 0.f;
            float h = fmaxf(nrm - 0.5f, 0.f);      // DELTA_V = 0.5
            float v = h * h;
            return (rawlab >= 0 && lvalid[l] > 0.5f) ? v : 0.f;
        };
        atomicAdd(&lvar[l0], hinge2(a0, lab4.x, l0));
        atomicAdd(&lvar[l1], hinge2(a1, lab4.y, l1));
        atomicAdd(&lvar[l2], hinge2(a2, lab4.z, l2));
        atomicAdd(&lvar[l3], hinge2(a3, lab4.w, l3));
    }
    __syncthreads();
    if (t < C) atomicAdd(&ws[WS_VAR + t], lvar[t]);
}

// Pass 4: final scalar. (unchanged)
__global__ void k4_final(const float* __restrict__ ws, float* __restrict__ out) {
    if (threadIdx.x == 0) {
        float loss_var = 0.f;
        for (int c = 0; c < C; ++c) {
            float cnt = ws[WS_CNT + c];
            float v = ws[WS_VAR + c] / fmaxf(cnt, 1.f);
            if (ws[WS_VALID + c] > 0.5f) loss_var += v;
        }
        float reg  = ws[WS_SCAL + 0];
        float dist = ws[WS_SCAL + 1];
        float tv   = ws[WS_SCAL + 2];
        float loss = loss_var / tv + dist / (tv * (tv - 1.0f)) + 0.001f * reg / tv;
        out[0] = loss;
    }
}

extern "C" void kernel_launch(void* const* d_in, const int* in_sizes, int n_in,
                              void* d_out, int out_size, void* d_ws, size_t ws_size,
                              hipStream_t stream) {
    const float* feats  = (const float*)d_in[0];
    const int*   labels = (const int*)d_in[1];
    float* ws  = (float*)d_ws;
    float* out = (float*)d_out;

    hipLaunchKernelGGL(k0_init,  dim3((WS_ZERO_END + 255) / 256), dim3(256), 0, stream, ws);
    hipLaunchKernelGGL(k1_sums,  dim3(K1_NB), dim3(TPB), 0, stream, feats, labels, ws);
    hipLaunchKernelGGL(k2_means, dim3(1),   dim3(TPB), 0, stream, ws);
    hipLaunchKernelGGL(k3_var,   dim3(K3_NB), dim3(TPB), 0, stream, feats, labels, ws);
    hipLaunchKernelGGL(k4_final, dim3(1),   dim3(64),  0, stream, ws, out);
}